// Round 18
// baseline (135.612 us; speedup 1.0000x reference)
//
#include <hip/hip_runtime.h>

typedef __bf16 bf16x8 __attribute__((ext_vector_type(8)));
typedef __bf16 bf16x4 __attribute__((ext_vector_type(4)));
typedef float  f32x4  __attribute__((ext_vector_type(4)));
typedef float  f32x2  __attribute__((ext_vector_type(2)));

constexpr int BN  = 262144;
constexpr int DIN = 100;
constexpr int DH  = 200;
constexpr int DZ  = 20;
constexpr int KCB = 512;
constexpr int NBLK = BN / 128;       // 2048 fused blocks

// ws byte offsets (16B-aligned)
constexpr size_t WS_W1F  = 0;        // [13 m][4 kk][512] bf16 = 53248 B
constexpr size_t WS_W2F  = 53248;    // [2 m2][8 kk][512] bf16 = 16384 B
constexpr size_t WS_CBF  = 69632;    // [32 ct][512] bf16 = 32768 B (k=20 slot = ||cb||^2)
constexpr size_t WS_WMUF = 102400;   // [2 m2][512] bf16 = 2048 B
constexpr size_t WS_WLVF = 104448;   // 2048 B
constexpr size_t WS_B1P  = 106496;   // 256 f32 (zero-padded)
constexpr size_t WS_B2P  = 107520;   // 32 f32
constexpr size_t WS_BMUP = 107648;   // 32 f32
constexpr size_t WS_BLVP = 107776;   // 32 f32
constexpr size_t WS_PART = 107904;   // 8192 f32 per-wave loss partials
constexpr size_t WS_CNT  = 140672;   // 1 u32 block-completion counter

constexpr int PN_W1 = 26624, PN_W2 = 8192, PN_CB = 16384, PN_WMU = 1024, PN_WLV = 1024;
constexpr int PN_TOT = PN_W1 + PN_W2 + PN_CB + PN_WMU + PN_WLV + 256 + 32 + 32 + 32;

__device__ __forceinline__ unsigned umin2(unsigned a, unsigned b) { return a < b ? a : b; }

// ---------------------------------------------------------------------------
// Prep: fragment packing (unchanged) + zero the completion counter each call.
// ---------------------------------------------------------------------------
__global__ __launch_bounds__(256) void prep_kernel(
    const float* __restrict__ W1, const float* __restrict__ b1,
    const float* __restrict__ W2, const float* __restrict__ b2,
    const float* __restrict__ cb,
    const float* __restrict__ Wmu, const float* __restrict__ bmu,
    const float* __restrict__ Wlv, const float* __restrict__ blv,
    unsigned char* __restrict__ ws)
{
    int e = blockIdx.x * 256 + threadIdx.x;
    if (e == 0) *(unsigned*)(ws + WS_CNT) = 0u;   // reset per call (graph-safe)
    if (e >= PN_TOT) return;
    __bf16* w1f  = (__bf16*)(ws + WS_W1F);
    __bf16* w2f  = (__bf16*)(ws + WS_W2F);
    __bf16* cbf  = (__bf16*)(ws + WS_CBF);
    __bf16* wmuf = (__bf16*)(ws + WS_WMUF);
    __bf16* wlvf = (__bf16*)(ws + WS_WLVF);
    float* b1p  = (float*)(ws + WS_B1P);
    float* b2p  = (float*)(ws + WS_B2P);
    float* bmup = (float*)(ws + WS_BMUP);
    float* blvp = (float*)(ws + WS_BLVP);

    if (e < PN_W1) {
        int j = e & 7, lane = (e >> 3) & 63, kk = (e >> 9) & 3, m = e >> 11;
        int n = m * 16 + (lane & 15);
        int k = kk * 32 + ((lane >> 4) << 3) + j;
        w1f[e] = (__bf16)((n < DH && k < DIN) ? W1[k * DH + n] : 0.f);
        return;
    }
    e -= PN_W1;
    if (e < PN_W2) {
        int j = e & 7, lane = (e >> 3) & 63, kk = (e >> 9) & 7, m2 = e >> 12;
        int n = m2 * 16 + (lane & 15);
        int k = kk * 32 + ((lane >> 4) << 3) + j;
        w2f[e] = (__bf16)((n < DZ && k < DH) ? W2[k * DZ + n] : 0.f);
        return;
    }
    e -= PN_W2;
    if (e < PN_CB) {
        int j = e & 7, lane = (e >> 3) & 63, ct = e >> 9;
        int code = ct * 16 + (lane & 15);
        int d = ((lane >> 4) << 3) + j;
        float v = 0.f;
        if (d < DZ) v = -2.f * cb[code * DZ + d];
        else if (d == DZ) {
            float s = 0.f;
            #pragma unroll
            for (int dd = 0; dd < DZ; ++dd) s = fmaf(cb[code * DZ + dd], cb[code * DZ + dd], s);
            v = s;
        }
        cbf[e] = (__bf16)v;
        return;
    }
    e -= PN_CB;
    if (e < PN_WMU) {
        int j = e & 7, lane = (e >> 3) & 63, m2 = e >> 9;
        int n = m2 * 16 + (lane & 15);
        int k = ((lane >> 4) << 3) + j;
        wmuf[e] = (__bf16)((n < DZ && k < DZ) ? Wmu[k * DZ + n] : 0.f);
        return;
    }
    e -= PN_WMU;
    if (e < PN_WLV) {
        int j = e & 7, lane = (e >> 3) & 63, m2 = e >> 9;
        int n = m2 * 16 + (lane & 15);
        int k = ((lane >> 4) << 3) + j;
        wlvf[e] = (__bf16)((n < DZ && k < DZ) ? Wlv[k * DZ + n] : 0.f);
        return;
    }
    e -= PN_WLV;
    if (e < 256) { b1p[e] = (e < DH) ? b1[e] : 0.f; return; }
    e -= 256;
    if (e < 32) { b2p[e] = (e < DZ) ? b2[e] : 0.f; return; }
    e -= 32;
    if (e < 32) { bmup[e] = (e < DZ) ? bmu[e] : 0.f; return; }
    e -= 32;
    blvp[e - 32] = (e - 32 < DZ) ? blv[e - 32] : 0.f;
}

// ---------------------------------------------------------------------------
// Fused main = r17 champion + merged last-block loss reduction (no separate
// loss_reduce kernel). 128 rows/block, 256 threads, 4 waves. LDS 32768 B.
// ---------------------------------------------------------------------------
__global__ __launch_bounds__(256) void fused_main(
    const float* __restrict__ c, const float* __restrict__ cb,
    unsigned char* __restrict__ ws, float* __restrict__ out,
    float* __restrict__ partials)
{
    __shared__ __align__(16) unsigned char region[32768];

    const __bf16* w1f  = (const __bf16*)(ws + WS_W1F);
    const __bf16* w2f  = (const __bf16*)(ws + WS_W2F);
    const __bf16* cbf  = (const __bf16*)(ws + WS_CBF);
    const __bf16* wmuf = (const __bf16*)(ws + WS_WMUF);
    const __bf16* wlvf = (const __bf16*)(ws + WS_WLVF);
    const float* b1p  = (const float*)(ws + WS_B1P);
    const float* b2p  = (const float*)(ws + WS_B2P);
    const float* bmup = (const float*)(ws + WS_BMUP);
    const float* blvp = (const float*)(ws + WS_BLVP);

    const int tid = threadIdx.x;
    const int l   = tid & 63;
    const int wid = __builtin_amdgcn_readfirstlane(tid >> 6);
    const int g   = l >> 4;
    const int li  = l & 15;
    const int rowB = blockIdx.x * 128;

    // ---- phase 0: cooperative coalesced c load -> cT (bf16, swizzled) ----
    {
        const float4* cbase = (const float4*)(c + (size_t)rowB * DIN);
        #pragma unroll
        for (int i = 0; i < 13; ++i) {
            int f4 = tid + i * 256;
            if (i < 12 || tid < 128) {
                float4 v = cbase[f4];
                int row = f4 / 25;
                int k4  = (f4 - row * 25) * 4;
                bf16x4 p;
                p[0] = (__bf16)v.x; p[1] = (__bf16)v.y;
                p[2] = (__bf16)v.z; p[3] = (__bf16)v.w;
                int byte = (k4 * 2) ^ ((row & 7) << 4);
                *(bf16x4*)(region + row * 256 + byte) = p;
            }
        }
        #pragma unroll
        for (int i = 0; i < 4; ++i) {
            int e = tid + i * 256;                     // 896 = 128 rows x 7 slots
            if (e < 896) {
                int row = e / 7, s = e - row * 7;
                int byte = (200 + s * 8) ^ ((row & 7) << 4);
                *(uint2*)(region + row * 256 + byte) = uint2{0u, 0u};
            }
        }
    }
    __syncthreads();

    // ---- c B-fragments from LDS (conflict-free ds_read_b128) ----
    bf16x8 cf0[4], cf1[4];
    #pragma unroll
    for (int nt = 0; nt < 2; ++nt) {
        const int row = wid * 32 + nt * 16 + li;
        const unsigned char* rb = region + row * 256;
        const int swz = (row & 7) << 4;
        #pragma unroll
        for (int kk = 0; kk < 4; ++kk) {
            bf16x8 a = *(const bf16x8*)(rb + ((kk * 64 + g * 16) ^ swz));
            if (nt == 0) cf0[kk] = a; else cf1[kk] = a;
        }
    }

    // GEMM2 accumulators z[m2][nt]
    f32x4 zm0n0, zm0n1, zm1n0, zm1n1;
    {
        f32x4 bz0 = *(const f32x4*)(b2p + g * 4);
        f32x4 bz1 = *(const f32x4*)(b2p + 16 + g * 4);
        zm0n0 = bz0; zm0n1 = bz0; zm1n0 = bz1; zm1n1 = bz1;
    }

    unsigned char* hW = region + wid * 8192;   // aliases this wave's own c rows
    const int swzH = (li & 7) << 4;

    // ---- two halves of hidden (128 cols each; tiles 13..15 are zero) ----
    #pragma unroll
    for (int hf = 0; hf < 2; ++hf) {
        #pragma unroll
        for (int t = 0; t < 8; ++t) {
            const int mg = hf * 8 + t;
            const int cbyte = (t * 32 + g * 8) ^ swzH;
            if (mg <= 12) {
                f32x4 acc0 = *(const f32x4*)(b1p + mg * 16 + g * 4);
                f32x4 acc1 = acc0;
                #pragma unroll
                for (int kk = 0; kk < 4; ++kk) {
                    bf16x8 aw = *(const bf16x8*)(w1f + ((mg * 4 + kk) * 512 + l * 8));
                    acc0 = __builtin_amdgcn_mfma_f32_16x16x32_bf16(aw, cf0[kk], acc0, 0, 0, 0);
                    acc1 = __builtin_amdgcn_mfma_f32_16x16x32_bf16(aw, cf1[kk], acc1, 0, 0, 0);
                }
                bf16x4 p0, p1;
                #pragma unroll
                for (int r = 0; r < 4; ++r) {
                    float h0 = acc0[r]; h0 = h0 > 0.f ? h0 : (__expf(h0) - 1.f);
                    float h1 = acc1[r]; h1 = h1 > 0.f ? h1 : (__expf(h1) - 1.f);
                    p0[r] = (__bf16)h0; p1[r] = (__bf16)h1;
                }
                *(bf16x4*)(hW + li * 256 + cbyte)        = p0;
                *(bf16x4*)(hW + (li + 16) * 256 + cbyte) = p1;
            } else {
                *(uint2*)(hW + li * 256 + cbyte)        = uint2{0u, 0u};
                *(uint2*)(hW + (li + 16) * 256 + cbyte) = uint2{0u, 0u};
            }
        }
        // GEMM2 partial over this half's 128-col K window
        #pragma unroll
        for (int kk = 0; kk < 4; ++kk) {
            const int kk2 = hf * 4 + kk;
            const int rb = (kk * 64 + g * 16) ^ swzH;
            bf16x8 hb0 = *(const bf16x8*)(hW + li * 256 + rb);
            bf16x8 hb1 = *(const bf16x8*)(hW + (li + 16) * 256 + rb);
            bf16x8 w20 = *(const bf16x8*)(w2f + ((0 * 8 + kk2) * 512 + l * 8));
            bf16x8 w21 = *(const bf16x8*)(w2f + ((1 * 8 + kk2) * 512 + l * 8));
            zm0n0 = __builtin_amdgcn_mfma_f32_16x16x32_bf16(w20, hb0, zm0n0, 0, 0, 0);
            zm0n1 = __builtin_amdgcn_mfma_f32_16x16x32_bf16(w20, hb1, zm0n1, 0, 0, 0);
            zm1n0 = __builtin_amdgcn_mfma_f32_16x16x32_bf16(w21, hb0, zm1n0, 0, 0, 0);
            zm1n1 = __builtin_amdgcn_mfma_f32_16x16x32_bf16(w21, hb1, zm1n1, 0, 0, 0);
        }
    }

    // ---- zT: first 2KB of own hW area (wave-private, in-order LDS) ----
    unsigned char* zB = hW;
    const int swzZ = (li & 3) << 4;
    {
        bf16x4 q;
        #pragma unroll
        for (int r = 0; r < 4; ++r) q[r] = (__bf16)zm0n0[r];
        *(bf16x4*)(zB + li * 64 + ((g * 8) ^ swzZ)) = q;
        #pragma unroll
        for (int r = 0; r < 4; ++r) q[r] = (__bf16)zm0n1[r];
        *(bf16x4*)(zB + (li + 16) * 64 + ((g * 8) ^ swzZ)) = q;
        bf16x4 t0;
        #pragma unroll
        for (int r = 0; r < 4; ++r) t0[r] = (__bf16)0.f;
        bf16x4 t1 = t0;
        if (g == 0) {
            #pragma unroll
            for (int r = 0; r < 4; ++r) { t0[r] = (__bf16)zm1n0[r]; t1[r] = (__bf16)zm1n1[r]; }
        } else if (g == 1) { t0[0] = (__bf16)1.0f; t1[0] = (__bf16)1.0f; }
        *(bf16x4*)(zB + li * 64 + ((32 + g * 8) ^ swzZ)) = t0;
        *(bf16x4*)(zB + (li + 16) * 64 + ((32 + g * 8) ^ swzZ)) = t1;
    }

    // ---- z B-fragments ----
    bf16x8 za0 = *(const bf16x8*)(zB + li * 64 + ((g * 16) ^ swzZ));
    bf16x8 za1 = *(const bf16x8*)(zB + (li + 16) * 64 + ((g * 16) ^ swzZ));
    __syncthreads();   // cT/hW/zT dead; region free

    // ---- stage cbf into LDS (exactly 32 KB), cooperative coalesced ----
    {
        const uint4* src = (const uint4*)cbf;
        uint4* dst = (uint4*)region;
        #pragma unroll
        for (int i = 0; i < 8; ++i)
            dst[tid + i * 256] = src[tid + i * 256];
    }
    __syncthreads();

    // ---- VQ from LDS: scores biased +1.0, packed uint keys ----
    unsigned run0 = 0xFFFFFFFFu, run1 = 0xFFFFFFFFu;
    f32x4 one4;
    one4[0] = 1.f; one4[1] = 1.f; one4[2] = 1.f; one4[3] = 1.f;
    #pragma unroll 8
    for (int ct = 0; ct < 32; ++ct) {
        bf16x8 cf = *(const bf16x8*)(region + ct * 1024 + l * 16);  // linear, conflict-free
        f32x4 s0 = __builtin_amdgcn_mfma_f32_16x16x32_bf16(cf, za0, one4, 0, 0, 0);
        f32x4 s1 = __builtin_amdgcn_mfma_f32_16x16x32_bf16(cf, za1, one4, 0, 0, 0);
        const unsigned ib = (unsigned)(ct * 16 + g * 4);
        unsigned k0 = (__float_as_uint(s0[0]) & ~511u) | (ib + 0);
        unsigned k1 = (__float_as_uint(s0[1]) & ~511u) | (ib + 1);
        unsigned k2 = (__float_as_uint(s0[2]) & ~511u) | (ib + 2);
        unsigned k3 = (__float_as_uint(s0[3]) & ~511u) | (ib + 3);
        run0 = umin2(umin2(k0, k1), umin2(umin2(k2, k3), run0));
        k0 = (__float_as_uint(s1[0]) & ~511u) | (ib + 0);
        k1 = (__float_as_uint(s1[1]) & ~511u) | (ib + 1);
        k2 = (__float_as_uint(s1[2]) & ~511u) | (ib + 2);
        k3 = (__float_as_uint(s1[3]) & ~511u) | (ib + 3);
        run1 = umin2(umin2(k0, k1), umin2(umin2(k2, k3), run1));
    }
    run0 = umin2(run0, (unsigned)__shfl_xor((int)run0, 16, 64));
    run0 = umin2(run0, (unsigned)__shfl_xor((int)run0, 32, 64));
    run1 = umin2(run1, (unsigned)__shfl_xor((int)run1, 16, 64));
    run1 = umin2(run1, (unsigned)__shfl_xor((int)run1, 32, 64));
    const int idx0 = (int)(run0 & 511u);
    const int idx1 = (int)(run1 & 511u);
    __syncthreads();   // VQ LDS reads done; region free for staging

    const size_t SEC = (size_t)BN * DZ;
    const size_t obase = (size_t)rowB * DZ;
    float* o_mu = out + obase;
    float* o_lv = out + SEC + obase;
    float* o_zq = out + 2 * SEC + obase;
    float* o_ze = out + 3 * SEC + obase;

    float* sA = (float*)region;
    float* sB = (float*)region + 2560;
    const int r0 = wid * 32 + li, r1 = r0 + 16;

    // ---- staging round A: mu first (4 accs), then lv (registers reused) ----
    {
        f32x4 bm0 = *(const f32x4*)(bmup + g * 4);
        f32x4 bm1 = *(const f32x4*)(bmup + 16 + g * 4);
        bf16x8 wm0 = *(const bf16x8*)(wmuf + (0 * 512 + l * 8));
        bf16x8 wm1 = *(const bf16x8*)(wmuf + (1 * 512 + l * 8));
        f32x4 a00 = __builtin_amdgcn_mfma_f32_16x16x32_bf16(wm0, za0, bm0, 0, 0, 0);
        f32x4 a01 = __builtin_amdgcn_mfma_f32_16x16x32_bf16(wm0, za1, bm0, 0, 0, 0);
        f32x4 a10 = __builtin_amdgcn_mfma_f32_16x16x32_bf16(wm1, za0, bm1, 0, 0, 0);
        f32x4 a11 = __builtin_amdgcn_mfma_f32_16x16x32_bf16(wm1, za1, bm1, 0, 0, 0);
        *(float4*)(sA + r0 * DZ + g * 4) = *(float4*)&a00;
        *(float4*)(sA + r1 * DZ + g * 4) = *(float4*)&a01;
        if (g == 0) {
            *(float4*)(sA + r0 * DZ + 16) = *(float4*)&a10;
            *(float4*)(sA + r1 * DZ + 16) = *(float4*)&a11;
        }
    }
    {
        f32x4 bv0 = *(const f32x4*)(blvp + g * 4);
        f32x4 bv1 = *(const f32x4*)(blvp + 16 + g * 4);
        bf16x8 wl0 = *(const bf16x8*)(wlvf + (0 * 512 + l * 8));
        bf16x8 wl1 = *(const bf16x8*)(wlvf + (1 * 512 + l * 8));
        f32x4 a00 = __builtin_amdgcn_mfma_f32_16x16x32_bf16(wl0, za0, bv0, 0, 0, 0);
        f32x4 a01 = __builtin_amdgcn_mfma_f32_16x16x32_bf16(wl0, za1, bv0, 0, 0, 0);
        f32x4 a10 = __builtin_amdgcn_mfma_f32_16x16x32_bf16(wl1, za0, bv1, 0, 0, 0);
        f32x4 a11 = __builtin_amdgcn_mfma_f32_16x16x32_bf16(wl1, za1, bv1, 0, 0, 0);
        *(float4*)(sB + r0 * DZ + g * 4) = *(float4*)&a00;
        *(float4*)(sB + r1 * DZ + g * 4) = *(float4*)&a01;
        if (g == 0) {
            *(float4*)(sB + r0 * DZ + 16) = *(float4*)&a10;
            *(float4*)(sB + r1 * DZ + 16) = *(float4*)&a11;
        }
    }
    __syncthreads();
    {
        int w4 = tid * 4;
        __builtin_nontemporal_store(*(const f32x4*)(sA + w4),        (f32x4*)(o_mu + w4));
        __builtin_nontemporal_store(*(const f32x4*)(sA + w4 + 1024), (f32x4*)(o_mu + w4 + 1024));
        __builtin_nontemporal_store(*(const f32x4*)(sB + w4),        (f32x4*)(o_lv + w4));
        __builtin_nontemporal_store(*(const f32x4*)(sB + w4 + 1024), (f32x4*)(o_lv + w4 + 1024));
        int w2 = tid * 2 + 2048;
        __builtin_nontemporal_store(*(const f32x2*)(sA + w2), (f32x2*)(o_mu + w2));
        __builtin_nontemporal_store(*(const f32x2*)(sB + w2), (f32x2*)(o_lv + w2));
    }
    __syncthreads();

    // ---- staging round B: gather zq + loss + ze ----
    float lsum = 0.f;
    {
        float4 q00 = *(const float4*)(cb + idx0 * DZ + g * 4);
        float4 q10 = *(const float4*)(cb + idx1 * DZ + g * 4);
        *(float4*)(sA + r0 * DZ + g * 4) = q00;
        *(float4*)(sA + r1 * DZ + g * 4) = q10;
        *(float4*)(sB + r0 * DZ + g * 4) = *(float4*)&zm0n0;
        *(float4*)(sB + r1 * DZ + g * 4) = *(float4*)&zm0n1;
        float d;
        d = q00.x - zm0n0[0]; lsum = fmaf(d, d, lsum);
        d = q00.y - zm0n0[1]; lsum = fmaf(d, d, lsum);
        d = q00.z - zm0n0[2]; lsum = fmaf(d, d, lsum);
        d = q00.w - zm0n0[3]; lsum = fmaf(d, d, lsum);
        d = q10.x - zm0n1[0]; lsum = fmaf(d, d, lsum);
        d = q10.y - zm0n1[1]; lsum = fmaf(d, d, lsum);
        d = q10.z - zm0n1[2]; lsum = fmaf(d, d, lsum);
        d = q10.w - zm0n1[3]; lsum = fmaf(d, d, lsum);
        if (g == 0) {
            float4 qe0 = *(const float4*)(cb + idx0 * DZ + 16);
            float4 qe1 = *(const float4*)(cb + idx1 * DZ + 16);
            *(float4*)(sA + r0 * DZ + 16) = qe0;
            *(float4*)(sA + r1 * DZ + 16) = qe1;
            *(float4*)(sB + r0 * DZ + 16) = *(float4*)&zm1n0;
            *(float4*)(sB + r1 * DZ + 16) = *(float4*)&zm1n1;
            d = qe0.x - zm1n0[0]; lsum = fmaf(d, d, lsum);
            d = qe0.y - zm1n0[1]; lsum = fmaf(d, d, lsum);
            d = qe0.z - zm1n0[2]; lsum = fmaf(d, d, lsum);
            d = qe0.w - zm1n0[3]; lsum = fmaf(d, d, lsum);
            d = qe1.x - zm1n1[0]; lsum = fmaf(d, d, lsum);
            d = qe1.y - zm1n1[1]; lsum = fmaf(d, d, lsum);
            d = qe1.z - zm1n1[2]; lsum = fmaf(d, d, lsum);
            d = qe1.w - zm1n1[3]; lsum = fmaf(d, d, lsum);
        }
    }
    #pragma unroll
    for (int off = 32; off > 0; off >>= 1) lsum += __shfl_down(lsum, off, 64);
    if (l == 0) partials[blockIdx.x * 4 + wid] = lsum;
    __syncthreads();
    {
        int w4 = tid * 4;
        __builtin_nontemporal_store(*(const f32x4*)(sA + w4),        (f32x4*)(o_zq + w4));
        __builtin_nontemporal_store(*(const f32x4*)(sA + w4 + 1024), (f32x4*)(o_zq + w4 + 1024));
        __builtin_nontemporal_store(*(const f32x4*)(sB + w4),        (f32x4*)(o_ze + w4));
        __builtin_nontemporal_store(*(const f32x4*)(sB + w4 + 1024), (f32x4*)(o_ze + w4 + 1024));
        int w2 = tid * 2 + 2048;
        __builtin_nontemporal_store(*(const f32x2*)(sA + w2), (f32x2*)(o_zq + w2));
        __builtin_nontemporal_store(*(const f32x2*)(sB + w2), (f32x2*)(o_ze + w2));
    }

    // ---- merged final loss reduction: last block reduces all partials ----
    // flag/wsum live in region bytes 20480.. (unused by sA/sB), LDS unchanged.
    unsigned* cnt   = (unsigned*)(ws + WS_CNT);
    unsigned* flagp = (unsigned*)(region + 20480);
    float*    wsum  = (float*)(region + 20496);
    if (tid == 0) {
        __threadfence();                              // publish this block's partials
        *flagp = (atomicAdd(cnt, 1u) == (unsigned)(NBLK - 1)) ? 1u : 0u;
    }
    __syncthreads();
    const unsigned isl = *flagp;                      // block-uniform
    float s = 0.f;
    if (isl) {
        __threadfence();                              // acquire all partials
        #pragma unroll
        for (int i = 0; i < 32; ++i) s += partials[tid + 256 * i];
    }
    #pragma unroll
    for (int off = 32; off > 0; off >>= 1) s += __shfl_down(s, off, 64);
    if (l == 0) wsum[wid] = s;
    __syncthreads();
    if (isl && tid == 0) {
        float total = (wsum[0] + wsum[1]) + (wsum[2] + wsum[3]);
        float ql = total / (float)((size_t)BN * DZ);
        float* o_loss = out + 4 * SEC;
        o_loss[0] = ql;           // quantization_loss
        o_loss[1] = 0.25f * ql;   // commitment_loss
    }
}

// ---------------------------------------------------------------------------
extern "C" void kernel_launch(void* const* d_in, const int* in_sizes, int n_in,
                              void* d_out, int out_size, void* d_ws, size_t ws_size,
                              hipStream_t stream) {
    const float* c   = (const float*)d_in[0];
    const float* W1  = (const float*)d_in[1];
    const float* b1  = (const float*)d_in[2];
    const float* W2  = (const float*)d_in[3];
    const float* b2  = (const float*)d_in[4];
    const float* cb  = (const float*)d_in[5];
    const float* Wmu = (const float*)d_in[6];
    const float* bmu = (const float*)d_in[7];
    const float* Wlv = (const float*)d_in[8];
    const float* blv = (const float*)d_in[9];
    float* out = (float*)d_out;
    unsigned char* ws = (unsigned char*)d_ws;
    float* partials = (float*)(ws + WS_PART);

    prep_kernel<<<(PN_TOT + 255) / 256, 256, 0, stream>>>(
        W1, b1, W2, b2, cb, Wmu, bmu, Wlv, blv, ws);
    fused_main<<<NBLK, 256, 0, stream>>>(c, cb, ws, out, partials);
}

// Round 19
// 71.963 us; speedup vs baseline: 1.8845x; 1.8845x over previous
//
#include <hip/hip_runtime.h>

typedef __bf16 bf16x8 __attribute__((ext_vector_type(8)));
typedef __bf16 bf16x4 __attribute__((ext_vector_type(4)));
typedef float  f32x4  __attribute__((ext_vector_type(4)));
typedef float  f32x2  __attribute__((ext_vector_type(2)));

constexpr int BN  = 262144;
constexpr int DIN = 100;
constexpr int DH  = 200;
constexpr int DZ  = 20;
constexpr int KCB = 512;

// ws byte offsets (16B-aligned)
constexpr size_t WS_W1F  = 0;        // [13 m][4 kk][512] bf16 = 53248 B
constexpr size_t WS_W2F  = 53248;    // [2 m2][8 kk][512] bf16 = 16384 B
constexpr size_t WS_CBF  = 69632;    // [32 ct][512] bf16 = 32768 B (k=20 slot = ||cb||^2)
constexpr size_t WS_WMUF = 102400;   // [2 m2][512] bf16 = 2048 B
constexpr size_t WS_WLVF = 104448;   // 2048 B
constexpr size_t WS_B1P  = 106496;   // 256 f32 (zero-padded)
constexpr size_t WS_B2P  = 107520;   // 32 f32
constexpr size_t WS_BMUP = 107648;   // 32 f32
constexpr size_t WS_BLVP = 107776;   // 32 f32
constexpr size_t WS_PART = 107904;   // 8192 f32 per-wave loss partials

constexpr int PN_W1 = 26624, PN_W2 = 8192, PN_CB = 16384, PN_WMU = 1024, PN_WLV = 1024;
constexpr int PN_TOT = PN_W1 + PN_W2 + PN_CB + PN_WMU + PN_WLV + 256 + 32 + 32 + 32;

__device__ __forceinline__ unsigned umin2(unsigned a, unsigned b) { return a < b ? a : b; }

// ---------------------------------------------------------------------------
// Prep: fragment packing.
// ---------------------------------------------------------------------------
__global__ __launch_bounds__(256) void prep_kernel(
    const float* __restrict__ W1, const float* __restrict__ b1,
    const float* __restrict__ W2, const float* __restrict__ b2,
    const float* __restrict__ cb,
    const float* __restrict__ Wmu, const float* __restrict__ bmu,
    const float* __restrict__ Wlv, const float* __restrict__ blv,
    unsigned char* __restrict__ ws)
{
    int e = blockIdx.x * 256 + threadIdx.x;
    if (e >= PN_TOT) return;
    __bf16* w1f  = (__bf16*)(ws + WS_W1F);
    __bf16* w2f  = (__bf16*)(ws + WS_W2F);
    __bf16* cbf  = (__bf16*)(ws + WS_CBF);
    __bf16* wmuf = (__bf16*)(ws + WS_WMUF);
    __bf16* wlvf = (__bf16*)(ws + WS_WLVF);
    float* b1p  = (float*)(ws + WS_B1P);
    float* b2p  = (float*)(ws + WS_B2P);
    float* bmup = (float*)(ws + WS_BMUP);
    float* blvp = (float*)(ws + WS_BLVP);

    if (e < PN_W1) {
        int j = e & 7, lane = (e >> 3) & 63, kk = (e >> 9) & 3, m = e >> 11;
        int n = m * 16 + (lane & 15);
        int k = kk * 32 + ((lane >> 4) << 3) + j;
        w1f[e] = (__bf16)((n < DH && k < DIN) ? W1[k * DH + n] : 0.f);
        return;
    }
    e -= PN_W1;
    if (e < PN_W2) {
        int j = e & 7, lane = (e >> 3) & 63, kk = (e >> 9) & 7, m2 = e >> 12;
        int n = m2 * 16 + (lane & 15);
        int k = kk * 32 + ((lane >> 4) << 3) + j;
        w2f[e] = (__bf16)((n < DZ && k < DH) ? W2[k * DZ + n] : 0.f);
        return;
    }
    e -= PN_W2;
    if (e < PN_CB) {
        int j = e & 7, lane = (e >> 3) & 63, ct = e >> 9;
        int code = ct * 16 + (lane & 15);
        int d = ((lane >> 4) << 3) + j;
        float v = 0.f;
        if (d < DZ) v = -2.f * cb[code * DZ + d];
        else if (d == DZ) {
            float s = 0.f;
            #pragma unroll
            for (int dd = 0; dd < DZ; ++dd) s = fmaf(cb[code * DZ + dd], cb[code * DZ + dd], s);
            v = s;
        }
        cbf[e] = (__bf16)v;
        return;
    }
    e -= PN_CB;
    if (e < PN_WMU) {
        int j = e & 7, lane = (e >> 3) & 63, m2 = e >> 9;
        int n = m2 * 16 + (lane & 15);
        int k = ((lane >> 4) << 3) + j;
        wmuf[e] = (__bf16)((n < DZ && k < DZ) ? Wmu[k * DZ + n] : 0.f);
        return;
    }
    e -= PN_WMU;
    if (e < PN_WLV) {
        int j = e & 7, lane = (e >> 3) & 63, m2 = e >> 9;
        int n = m2 * 16 + (lane & 15);
        int k = ((lane >> 4) << 3) + j;
        wlvf[e] = (__bf16)((n < DZ && k < DZ) ? Wlv[k * DZ + n] : 0.f);
        return;
    }
    e -= PN_WLV;
    if (e < 256) { b1p[e] = (e < DH) ? b1[e] : 0.f; return; }
    e -= 256;
    if (e < 32) { b2p[e] = (e < DZ) ? b2[e] : 0.f; return; }
    e -= 32;
    if (e < 32) { bmup[e] = (e < DZ) ? bmu[e] : 0.f; return; }
    e -= 32;
    blvp[e - 32] = (e - 32 < DZ) ? blv[e - 32] : 0.f;
}

// ---------------------------------------------------------------------------
// Fused main (champion): 128 rows/block, 256 threads, 4 waves, 32 rows/wave.
// LDS 32768 B, phase-aliased:
//   phase 0: cT [128][256 B] bf16 XOR-swizzled (coalesced cooperative load)
//   phase 1: hW aliases own wave's cT rows; zT aliases own hW
//   phase 2: cbf staged into region (32 KB) -> VQ from LDS
//   phase 3: staged output, two rounds ({mu,lv} then {zq,ze} + gather/loss)
// ---------------------------------------------------------------------------
__global__ __launch_bounds__(256) void fused_main(
    const float* __restrict__ c, const float* __restrict__ cb,
    const unsigned char* __restrict__ ws, float* __restrict__ out,
    float* __restrict__ partials)
{
    __shared__ __align__(16) unsigned char region[32768];

    const __bf16* w1f  = (const __bf16*)(ws + WS_W1F);
    const __bf16* w2f  = (const __bf16*)(ws + WS_W2F);
    const __bf16* cbf  = (const __bf16*)(ws + WS_CBF);
    const __bf16* wmuf = (const __bf16*)(ws + WS_WMUF);
    const __bf16* wlvf = (const __bf16*)(ws + WS_WLVF);
    const float* b1p  = (const float*)(ws + WS_B1P);
    const float* b2p  = (const float*)(ws + WS_B2P);
    const float* bmup = (const float*)(ws + WS_BMUP);
    const float* blvp = (const float*)(ws + WS_BLVP);

    const int tid = threadIdx.x;
    const int l   = tid & 63;
    const int wid = __builtin_amdgcn_readfirstlane(tid >> 6);
    const int g   = l >> 4;
    const int li  = l & 15;
    const int rowB = blockIdx.x * 128;

    // ---- phase 0: cooperative coalesced c load -> cT (bf16, swizzled) ----
    {
        const float4* cbase = (const float4*)(c + (size_t)rowB * DIN);
        #pragma unroll
        for (int i = 0; i < 13; ++i) {
            int f4 = tid + i * 256;
            if (i < 12 || tid < 128) {
                float4 v = cbase[f4];
                int row = f4 / 25;
                int k4  = (f4 - row * 25) * 4;
                bf16x4 p;
                p[0] = (__bf16)v.x; p[1] = (__bf16)v.y;
                p[2] = (__bf16)v.z; p[3] = (__bf16)v.w;
                int byte = (k4 * 2) ^ ((row & 7) << 4);
                *(bf16x4*)(region + row * 256 + byte) = p;
            }
        }
        #pragma unroll
        for (int i = 0; i < 4; ++i) {
            int e = tid + i * 256;                     // 896 = 128 rows x 7 slots
            if (e < 896) {
                int row = e / 7, s = e - row * 7;
                int byte = (200 + s * 8) ^ ((row & 7) << 4);
                *(uint2*)(region + row * 256 + byte) = uint2{0u, 0u};
            }
        }
    }
    __syncthreads();

    // ---- c B-fragments from LDS (conflict-free ds_read_b128) ----
    bf16x8 cf0[4], cf1[4];
    #pragma unroll
    for (int nt = 0; nt < 2; ++nt) {
        const int row = wid * 32 + nt * 16 + li;
        const unsigned char* rb = region + row * 256;
        const int swz = (row & 7) << 4;
        #pragma unroll
        for (int kk = 0; kk < 4; ++kk) {
            bf16x8 a = *(const bf16x8*)(rb + ((kk * 64 + g * 16) ^ swz));
            if (nt == 0) cf0[kk] = a; else cf1[kk] = a;
        }
    }

    // GEMM2 accumulators z[m2][nt]
    f32x4 zm0n0, zm0n1, zm1n0, zm1n1;
    {
        f32x4 bz0 = *(const f32x4*)(b2p + g * 4);
        f32x4 bz1 = *(const f32x4*)(b2p + 16 + g * 4);
        zm0n0 = bz0; zm0n1 = bz0; zm1n0 = bz1; zm1n1 = bz1;
    }

    unsigned char* hW = region + wid * 8192;   // aliases this wave's own c rows
    const int swzH = (li & 7) << 4;

    // ---- two halves of hidden (128 cols each; tiles 13..15 are zero) ----
    #pragma unroll
    for (int hf = 0; hf < 2; ++hf) {
        #pragma unroll
        for (int t = 0; t < 8; ++t) {
            const int mg = hf * 8 + t;
            const int cbyte = (t * 32 + g * 8) ^ swzH;
            if (mg <= 12) {
                f32x4 acc0 = *(const f32x4*)(b1p + mg * 16 + g * 4);
                f32x4 acc1 = acc0;
                #pragma unroll
                for (int kk = 0; kk < 4; ++kk) {
                    bf16x8 aw = *(const bf16x8*)(w1f + ((mg * 4 + kk) * 512 + l * 8));
                    acc0 = __builtin_amdgcn_mfma_f32_16x16x32_bf16(aw, cf0[kk], acc0, 0, 0, 0);
                    acc1 = __builtin_amdgcn_mfma_f32_16x16x32_bf16(aw, cf1[kk], acc1, 0, 0, 0);
                }
                bf16x4 p0, p1;
                #pragma unroll
                for (int r = 0; r < 4; ++r) {
                    float h0 = acc0[r]; h0 = h0 > 0.f ? h0 : (__expf(h0) - 1.f);
                    float h1 = acc1[r]; h1 = h1 > 0.f ? h1 : (__expf(h1) - 1.f);
                    p0[r] = (__bf16)h0; p1[r] = (__bf16)h1;
                }
                *(bf16x4*)(hW + li * 256 + cbyte)        = p0;
                *(bf16x4*)(hW + (li + 16) * 256 + cbyte) = p1;
            } else {
                *(uint2*)(hW + li * 256 + cbyte)        = uint2{0u, 0u};
                *(uint2*)(hW + (li + 16) * 256 + cbyte) = uint2{0u, 0u};
            }
        }
        // GEMM2 partial over this half's 128-col K window
        #pragma unroll
        for (int kk = 0; kk < 4; ++kk) {
            const int kk2 = hf * 4 + kk;
            const int rb = (kk * 64 + g * 16) ^ swzH;
            bf16x8 hb0 = *(const bf16x8*)(hW + li * 256 + rb);
            bf16x8 hb1 = *(const bf16x8*)(hW + (li + 16) * 256 + rb);
            bf16x8 w20 = *(const bf16x8*)(w2f + ((0 * 8 + kk2) * 512 + l * 8));
            bf16x8 w21 = *(const bf16x8*)(w2f + ((1 * 8 + kk2) * 512 + l * 8));
            zm0n0 = __builtin_amdgcn_mfma_f32_16x16x32_bf16(w20, hb0, zm0n0, 0, 0, 0);
            zm0n1 = __builtin_amdgcn_mfma_f32_16x16x32_bf16(w20, hb1, zm0n1, 0, 0, 0);
            zm1n0 = __builtin_amdgcn_mfma_f32_16x16x32_bf16(w21, hb0, zm1n0, 0, 0, 0);
            zm1n1 = __builtin_amdgcn_mfma_f32_16x16x32_bf16(w21, hb1, zm1n1, 0, 0, 0);
        }
    }

    // ---- zT: first 2KB of own hW area (wave-private, in-order LDS) ----
    unsigned char* zB = hW;
    const int swzZ = (li & 3) << 4;
    {
        bf16x4 q;
        #pragma unroll
        for (int r = 0; r < 4; ++r) q[r] = (__bf16)zm0n0[r];
        *(bf16x4*)(zB + li * 64 + ((g * 8) ^ swzZ)) = q;
        #pragma unroll
        for (int r = 0; r < 4; ++r) q[r] = (__bf16)zm0n1[r];
        *(bf16x4*)(zB + (li + 16) * 64 + ((g * 8) ^ swzZ)) = q;
        bf16x4 t0;
        #pragma unroll
        for (int r = 0; r < 4; ++r) t0[r] = (__bf16)0.f;
        bf16x4 t1 = t0;
        if (g == 0) {
            #pragma unroll
            for (int r = 0; r < 4; ++r) { t0[r] = (__bf16)zm1n0[r]; t1[r] = (__bf16)zm1n1[r]; }
        } else if (g == 1) { t0[0] = (__bf16)1.0f; t1[0] = (__bf16)1.0f; }
        *(bf16x4*)(zB + li * 64 + ((32 + g * 8) ^ swzZ)) = t0;
        *(bf16x4*)(zB + (li + 16) * 64 + ((32 + g * 8) ^ swzZ)) = t1;
    }

    // ---- z B-fragments ----
    bf16x8 za0 = *(const bf16x8*)(zB + li * 64 + ((g * 16) ^ swzZ));
    bf16x8 za1 = *(const bf16x8*)(zB + (li + 16) * 64 + ((g * 16) ^ swzZ));
    __syncthreads();   // cT/hW/zT dead; region free

    // ---- stage cbf into LDS (exactly 32 KB), cooperative coalesced ----
    {
        const uint4* src = (const uint4*)cbf;
        uint4* dst = (uint4*)region;
        #pragma unroll
        for (int i = 0; i < 8; ++i)
            dst[tid + i * 256] = src[tid + i * 256];
    }
    __syncthreads();

    // ---- VQ from LDS: scores biased +1.0, packed uint keys ----
    unsigned run0 = 0xFFFFFFFFu, run1 = 0xFFFFFFFFu;
    f32x4 one4;
    one4[0] = 1.f; one4[1] = 1.f; one4[2] = 1.f; one4[3] = 1.f;
    #pragma unroll 8
    for (int ct = 0; ct < 32; ++ct) {
        bf16x8 cf = *(const bf16x8*)(region + ct * 1024 + l * 16);  // linear, conflict-free
        f32x4 s0 = __builtin_amdgcn_mfma_f32_16x16x32_bf16(cf, za0, one4, 0, 0, 0);
        f32x4 s1 = __builtin_amdgcn_mfma_f32_16x16x32_bf16(cf, za1, one4, 0, 0, 0);
        const unsigned ib = (unsigned)(ct * 16 + g * 4);
        unsigned k0 = (__float_as_uint(s0[0]) & ~511u) | (ib + 0);
        unsigned k1 = (__float_as_uint(s0[1]) & ~511u) | (ib + 1);
        unsigned k2 = (__float_as_uint(s0[2]) & ~511u) | (ib + 2);
        unsigned k3 = (__float_as_uint(s0[3]) & ~511u) | (ib + 3);
        run0 = umin2(umin2(k0, k1), umin2(umin2(k2, k3), run0));
        k0 = (__float_as_uint(s1[0]) & ~511u) | (ib + 0);
        k1 = (__float_as_uint(s1[1]) & ~511u) | (ib + 1);
        k2 = (__float_as_uint(s1[2]) & ~511u) | (ib + 2);
        k3 = (__float_as_uint(s1[3]) & ~511u) | (ib + 3);
        run1 = umin2(umin2(k0, k1), umin2(umin2(k2, k3), run1));
    }
    run0 = umin2(run0, (unsigned)__shfl_xor((int)run0, 16, 64));
    run0 = umin2(run0, (unsigned)__shfl_xor((int)run0, 32, 64));
    run1 = umin2(run1, (unsigned)__shfl_xor((int)run1, 16, 64));
    run1 = umin2(run1, (unsigned)__shfl_xor((int)run1, 32, 64));
    const int idx0 = (int)(run0 & 511u);
    const int idx1 = (int)(run1 & 511u);
    __syncthreads();   // VQ LDS reads done; region free for staging

    const size_t SEC = (size_t)BN * DZ;
    const size_t obase = (size_t)rowB * DZ;
    float* o_mu = out + obase;
    float* o_lv = out + SEC + obase;
    float* o_zq = out + 2 * SEC + obase;
    float* o_ze = out + 3 * SEC + obase;

    float* sA = (float*)region;
    float* sB = (float*)region + 2560;
    const int r0 = wid * 32 + li, r1 = r0 + 16;

    // ---- staging round A: mu first (4 accs), then lv (registers reused) ----
    {
        f32x4 bm0 = *(const f32x4*)(bmup + g * 4);
        f32x4 bm1 = *(const f32x4*)(bmup + 16 + g * 4);
        bf16x8 wm0 = *(const bf16x8*)(wmuf + (0 * 512 + l * 8));
        bf16x8 wm1 = *(const bf16x8*)(wmuf + (1 * 512 + l * 8));
        f32x4 a00 = __builtin_amdgcn_mfma_f32_16x16x32_bf16(wm0, za0, bm0, 0, 0, 0);
        f32x4 a01 = __builtin_amdgcn_mfma_f32_16x16x32_bf16(wm0, za1, bm0, 0, 0, 0);
        f32x4 a10 = __builtin_amdgcn_mfma_f32_16x16x32_bf16(wm1, za0, bm1, 0, 0, 0);
        f32x4 a11 = __builtin_amdgcn_mfma_f32_16x16x32_bf16(wm1, za1, bm1, 0, 0, 0);
        *(float4*)(sA + r0 * DZ + g * 4) = *(float4*)&a00;
        *(float4*)(sA + r1 * DZ + g * 4) = *(float4*)&a01;
        if (g == 0) {
            *(float4*)(sA + r0 * DZ + 16) = *(float4*)&a10;
            *(float4*)(sA + r1 * DZ + 16) = *(float4*)&a11;
        }
    }
    {
        f32x4 bv0 = *(const f32x4*)(blvp + g * 4);
        f32x4 bv1 = *(const f32x4*)(blvp + 16 + g * 4);
        bf16x8 wl0 = *(const bf16x8*)(wlvf + (0 * 512 + l * 8));
        bf16x8 wl1 = *(const bf16x8*)(wlvf + (1 * 512 + l * 8));
        f32x4 a00 = __builtin_amdgcn_mfma_f32_16x16x32_bf16(wl0, za0, bv0, 0, 0, 0);
        f32x4 a01 = __builtin_amdgcn_mfma_f32_16x16x32_bf16(wl0, za1, bv0, 0, 0, 0);
        f32x4 a10 = __builtin_amdgcn_mfma_f32_16x16x32_bf16(wl1, za0, bv1, 0, 0, 0);
        f32x4 a11 = __builtin_amdgcn_mfma_f32_16x16x32_bf16(wl1, za1, bv1, 0, 0, 0);
        *(float4*)(sB + r0 * DZ + g * 4) = *(float4*)&a00;
        *(float4*)(sB + r1 * DZ + g * 4) = *(float4*)&a01;
        if (g == 0) {
            *(float4*)(sB + r0 * DZ + 16) = *(float4*)&a10;
            *(float4*)(sB + r1 * DZ + 16) = *(float4*)&a11;
        }
    }
    __syncthreads();
    // float4 copy-out: 2560 f32 per array = 2 x float4 + 1 x float2 per thread
    {
        int w4 = tid * 4;
        __builtin_nontemporal_store(*(const f32x4*)(sA + w4),        (f32x4*)(o_mu + w4));
        __builtin_nontemporal_store(*(const f32x4*)(sA + w4 + 1024), (f32x4*)(o_mu + w4 + 1024));
        __builtin_nontemporal_store(*(const f32x4*)(sB + w4),        (f32x4*)(o_lv + w4));
        __builtin_nontemporal_store(*(const f32x4*)(sB + w4 + 1024), (f32x4*)(o_lv + w4 + 1024));
        int w2 = tid * 2 + 2048;
        __builtin_nontemporal_store(*(const f32x2*)(sA + w2), (f32x2*)(o_mu + w2));
        __builtin_nontemporal_store(*(const f32x2*)(sB + w2), (f32x2*)(o_lv + w2));
    }
    __syncthreads();

    // ---- staging round B: gather zq + loss + ze ----
    float lsum = 0.f;
    {
        float4 q00 = *(const float4*)(cb + idx0 * DZ + g * 4);
        float4 q10 = *(const float4*)(cb + idx1 * DZ + g * 4);
        *(float4*)(sA + r0 * DZ + g * 4) = q00;
        *(float4*)(sA + r1 * DZ + g * 4) = q10;
        *(float4*)(sB + r0 * DZ + g * 4) = *(float4*)&zm0n0;
        *(float4*)(sB + r1 * DZ + g * 4) = *(float4*)&zm0n1;
        float d;
        d = q00.x - zm0n0[0]; lsum = fmaf(d, d, lsum);
        d = q00.y - zm0n0[1]; lsum = fmaf(d, d, lsum);
        d = q00.z - zm0n0[2]; lsum = fmaf(d, d, lsum);
        d = q00.w - zm0n0[3]; lsum = fmaf(d, d, lsum);
        d = q10.x - zm0n1[0]; lsum = fmaf(d, d, lsum);
        d = q10.y - zm0n1[1]; lsum = fmaf(d, d, lsum);
        d = q10.z - zm0n1[2]; lsum = fmaf(d, d, lsum);
        d = q10.w - zm0n1[3]; lsum = fmaf(d, d, lsum);
        if (g == 0) {
            float4 qe0 = *(const float4*)(cb + idx0 * DZ + 16);
            float4 qe1 = *(const float4*)(cb + idx1 * DZ + 16);
            *(float4*)(sA + r0 * DZ + 16) = qe0;
            *(float4*)(sA + r1 * DZ + 16) = qe1;
            *(float4*)(sB + r0 * DZ + 16) = *(float4*)&zm1n0;
            *(float4*)(sB + r1 * DZ + 16) = *(float4*)&zm1n1;
            d = qe0.x - zm1n0[0]; lsum = fmaf(d, d, lsum);
            d = qe0.y - zm1n0[1]; lsum = fmaf(d, d, lsum);
            d = qe0.z - zm1n0[2]; lsum = fmaf(d, d, lsum);
            d = qe0.w - zm1n0[3]; lsum = fmaf(d, d, lsum);
            d = qe1.x - zm1n1[0]; lsum = fmaf(d, d, lsum);
            d = qe1.y - zm1n1[1]; lsum = fmaf(d, d, lsum);
            d = qe1.z - zm1n1[2]; lsum = fmaf(d, d, lsum);
            d = qe1.w - zm1n1[3]; lsum = fmaf(d, d, lsum);
        }
    }
    #pragma unroll
    for (int off = 32; off > 0; off >>= 1) lsum += __shfl_down(lsum, off, 64);
    if (l == 0) partials[blockIdx.x * 4 + wid] = lsum;
    __syncthreads();
    {
        int w4 = tid * 4;
        __builtin_nontemporal_store(*(const f32x4*)(sA + w4),        (f32x4*)(o_zq + w4));
        __builtin_nontemporal_store(*(const f32x4*)(sA + w4 + 1024), (f32x4*)(o_zq + w4 + 1024));
        __builtin_nontemporal_store(*(const f32x4*)(sB + w4),        (f32x4*)(o_ze + w4));
        __builtin_nontemporal_store(*(const f32x4*)(sB + w4 + 1024), (f32x4*)(o_ze + w4 + 1024));
        int w2 = tid * 2 + 2048;
        __builtin_nontemporal_store(*(const f32x2*)(sA + w2), (f32x2*)(o_zq + w2));
        __builtin_nontemporal_store(*(const f32x2*)(sB + w2), (f32x2*)(o_ze + w2));
    }
}

// ---------------------------------------------------------------------------
// Final reduction: 8192 per-wave partials -> two scalar losses (deterministic)
// ---------------------------------------------------------------------------
__global__ __launch_bounds__(256) void loss_reduce(const float* __restrict__ partials,
                                                   float* __restrict__ out_scalars) {
    int t = threadIdx.x;
    float s = 0.f;
    #pragma unroll
    for (int i = 0; i < 32; ++i) s += partials[t + 256 * i];
    #pragma unroll
    for (int off = 32; off > 0; off >>= 1) s += __shfl_down(s, off, 64);
    __shared__ float wsum[4];
    if ((t & 63) == 0) wsum[t >> 6] = s;
    __syncthreads();
    if (t == 0) {
        float total = (wsum[0] + wsum[1]) + (wsum[2] + wsum[3]);
        float ql = total / (float)((size_t)BN * DZ);
        out_scalars[0] = ql;          // quantization_loss
        out_scalars[1] = 0.25f * ql;  // commitment_loss
    }
}

// ---------------------------------------------------------------------------
extern "C" void kernel_launch(void* const* d_in, const int* in_sizes, int n_in,
                              void* d_out, int out_size, void* d_ws, size_t ws_size,
                              hipStream_t stream) {
    const float* c   = (const float*)d_in[0];
    const float* W1  = (const float*)d_in[1];
    const float* b1  = (const float*)d_in[2];
    const float* W2  = (const float*)d_in[3];
    const float* b2  = (const float*)d_in[4];
    const float* cb  = (const float*)d_in[5];
    const float* Wmu = (const float*)d_in[6];
    const float* bmu = (const float*)d_in[7];
    const float* Wlv = (const float*)d_in[8];
    const float* blv = (const float*)d_in[9];
    float* out = (float*)d_out;
    unsigned char* ws = (unsigned char*)d_ws;
    float* partials = (float*)(ws + WS_PART);

    prep_kernel<<<(PN_TOT + 255) / 256, 256, 0, stream>>>(
        W1, b1, W2, b2, cb, Wmu, bmu, Wlv, blv, ws);
    fused_main<<<BN / 128, 256, 0, stream>>>(c, cb, ws, out, partials);
    loss_reduce<<<1, 256, 0, stream>>>(partials, out + 4 * (size_t)BN * DZ);
}